// Round 4
// baseline (827.053 us; speedup 1.0000x reference)
//
#include <hip/hip_runtime.h>
#include <cstddef>

#define NCF 10

struct TFKeys { unsigned k[2 * NCF]; };

typedef __attribute__((ext_vector_type(8))) _Float16 f16x8;
typedef __attribute__((ext_vector_type(4))) float f32x4;

// Threefry-2x32, 20 rounds (JAX-compatible, partitionable semantics verified R1).
__host__ __device__ __forceinline__ void tf2x32(unsigned k0, unsigned k1,
                                                unsigned x0, unsigned x1,
                                                unsigned& o0, unsigned& o1) {
  const unsigned ks2 = k0 ^ k1 ^ 0x1BD11BDAu;
  x0 += k0; x1 += k1;
#define TF_R(r) x0 += x1; x1 = (x1 << (r)) | (x1 >> (32 - (r))); x1 ^= x0;
  TF_R(13) TF_R(15) TF_R(26) TF_R(6)
  x0 += k1;  x1 += ks2 + 1u;
  TF_R(17) TF_R(29) TF_R(16) TF_R(24)
  x0 += ks2; x1 += k0 + 2u;
  TF_R(13) TF_R(15) TF_R(26) TF_R(6)
  x0 += k0;  x1 += k1 + 3u;
  TF_R(17) TF_R(29) TF_R(16) TF_R(24)
  x0 += k1;  x1 += ks2 + 4u;
  TF_R(13) TF_R(15) TF_R(26) TF_R(6)
  x0 += ks2; x1 += k0 + 5u;
#undef TF_R
  o0 = x0; o1 = x1;
}

__device__ __forceinline__ float u01(unsigned bits) {
  return __uint_as_float((bits >> 9) | 0x3f800000u) - 1.0f;
}

// fp16x3 split of 8 floats: x = hi + lo, |x - hi - lo| <= 2^-24 |x|.
__device__ __forceinline__ void split44(const float4 a, const float4 b,
                                        f16x8& hh, f16x8& ll) {
  const float v[8] = {a.x, a.y, a.z, a.w, b.x, b.y, b.z, b.w};
#pragma unroll
  for (int e = 0; e < 8; ++e) {
    const _Float16 h = (_Float16)v[e];
    hh[e] = h;
    ll[e] = (_Float16)(v[e] - (float)h);
  }
}

// D += Ah*Bh + Ah*Bl + Al*Bh  (drops Al*Bl ~ 2^-24)
#define MFMA3(acc, ah, al, bh, bl)                                          \
  acc = __builtin_amdgcn_mfma_f32_16x16x32_f16(ah, bh, acc, 0, 0, 0);       \
  acc = __builtin_amdgcn_mfma_f32_16x16x32_f16(ah, bl, acc, 0, 0, 0);       \
  acc = __builtin_amdgcn_mfma_f32_16x16x32_f16(al, bh, acc, 0, 0, 0);

// Stage W[K][N] (row-major f32) into hi/lo B-fragment layout (verified R2):
// frag elem ((kt*NTN+nt)*64+lane)*8+e  <->  W[kt*32+(lane>>4)*8+e][nt*16+(lane&15)]
template <int K, int N, int NT>
__device__ __forceinline__ void stage_frags(const float* __restrict__ W,
                                            _Float16* fh, _Float16* fl, int t) {
  constexpr int NTN = N / 16;
  for (int i = t; i < K * N; i += NT) {
    const int e = i & 7, lane = (i >> 3) & 63, tile = i >> 9;
    const int kt = tile / NTN, nt = tile % NTN;
    const int k = kt * 32 + ((lane >> 4) << 3) + e;
    const int c = nt * 16 + (lane & 15);
    const float w = W[k * N + c];
    const _Float16 h = (_Float16)w;
    fh[i] = h;
    fl[i] = (_Float16)(w - (float)h);
  }
}

// [16][32] chunk buffer with XOR swizzle: naive layout is a 16-way bank
// conflict on the b128 reads (16 lanes stride 128B); swizzled -> 2-way (free).
__device__ __forceinline__ int swz(int row, int col) {
  return (row << 5) + (col ^ ((row & 7) << 2));
}

// ---------------------------------------------------------------------------
// Fused kernel, 1024 threads = 16 INDEPENDENT waves (16 samples each) sharing
// one 80KB weight-frag copy. Per-wave h round-trips chunked through a 2KB
// swizzled LDS buffer (in-order DS per wave => no barriers in the pass loop).
// LDS 112KB -> 1 block/CU = 16 waves/CU = 4 waves/SIMD (2x occupancy vs R3).
// VGPR must be <=128 for that: chunking shrinks live state (a1: 32->8 regs).
// ---------------------------------------------------------------------------
__global__ __launch_bounds__(1024, 4)
void infl_fused(const float* __restrict__ obs, const float* __restrict__ actions,
                const float* __restrict__ W1, const float* __restrict__ b1,
                const float* __restrict__ W2, const float* __restrict__ b2,
                const float* __restrict__ W3, const float* __restrict__ b3,
                float* __restrict__ out, TFKeys keys) {
  // Prologue: [0,65536) = W1-obs half frags (hi 32KB @0, lo 32KB @32768).
  // Pass loop: [0,81920) = pass-weight frags; [81920,114688) = 16 x 2KB chunk bufs.
  __shared__ __align__(16) unsigned char smem[114688];
  _Float16* w1oh = (_Float16*)smem;
  _Float16* w1ol = (_Float16*)(smem + 32768);
  _Float16* w1h  = (_Float16*)smem;                   // W1-act 64x128 hi (16KB)
  _Float16* w1l  = (_Float16*)(smem + 16384);
  _Float16* w2h  = (_Float16*)(smem + 32768);         // W2 128x64 hi (16KB)
  _Float16* w2l  = (_Float16*)(smem + 49152);
  _Float16* w3h  = (_Float16*)(smem + 65536);         // W3 64x64 hi (8KB)
  _Float16* w3l  = (_Float16*)(smem + 73728);

  const int t = threadIdx.x, wave = t >> 6, lane = t & 63;
  const int R0 = blockIdx.x * 256 + wave * 16;
  const int cA = lane & 15;            // A-row / C-D col
  const int kg = (lane >> 4) << 3;     // k base within 32-k tile
  const int r0 = (lane >> 4) << 2;     // C/D row base
  float* cb = (float*)(smem + 81920 + wave * 2048);   // per-wave [16][32] swizzled

  // ================= prologue: ho = b1 + obs @ W1[0:256] ==================
  f32x4 ho[8];
#pragma unroll
  for (int nt = 0; nt < 8; ++nt) {
    const float bv = b1[nt * 16 + cA];
    ho[nt] = (f32x4){bv, bv, bv, bv};
  }
  {
    const float* orow = obs + (size_t)(R0 + cA) * 256;
    for (int half = 0; half < 2; ++half) {
      __syncthreads();   // previous half's MFMAs done reading frags
      stage_frags<128, 128, 1024>(W1 + half * 128 * 128, w1oh, w1ol, t);
      __syncthreads();
#pragma unroll
      for (int kt = 0; kt < 4; ++kt) {
        const float4 va = *(const float4*)(orow + half * 128 + kt * 32 + kg);
        const float4 vb = *(const float4*)(orow + half * 128 + kt * 32 + kg + 4);
        f16x8 oh, ol;
        split44(va, vb, oh, ol);
#pragma unroll
        for (int nt = 0; nt < 8; ++nt) {
          const int tile = kt * 8 + nt;
          const f16x8 bh = *(const f16x8*)&w1oh[(tile * 64 + lane) * 8];
          const f16x8 bl = *(const f16x8*)&w1ol[(tile * 64 + lane) * 8];
          MFMA3(ho[nt], oh, ol, bh, bl)
        }
      }
    }
  }
  __syncthreads();   // prologue reads done; restage pass weights

  stage_frags<64, 128, 1024>(W1 + 256 * 128, w1h, w1l, t);
  stage_frags<128, 64, 1024>(W2, w2h, w2l, t);
  stage_frags<64, 64, 1024>(W3, w3h, w3l, t);

  float b2r[4], b3r[4];
#pragma unroll
  for (int nt = 0; nt < 4; ++nt) {
    b2r[nt] = b2[nt * 16 + cA];
    b3r[nt] = b3[nt * 16 + cA];
  }
  __syncthreads();   // last barrier of the kernel

  // ================= MLP body (one pass), chunked round-trips =============
  // h1 in 4 chunks of 32 k: L1 produces 2 tiles -> cb -> L2 partial (kt=c).
  // h2 in 2 chunks of 32 k: -> cb -> L3 (kt=d). Single cb reused; per-wave
  // in-order DS makes WAR safe without barriers.
#define MLP_BODY(HAS_ACT, acc3)                                              \
  {                                                                          \
    f32x4 a2[4];                                                             \
    _Pragma("unroll") for (int n2 = 0; n2 < 4; ++n2)                         \
      a2[n2] = (f32x4){b2r[n2], b2r[n2], b2r[n2], b2r[n2]};                  \
    _Pragma("unroll") for (int c = 0; c < 4; ++c) {                          \
      f32x4 a10 = ho[2 * c], a11 = ho[2 * c + 1];                            \
      if (HAS_ACT) {                                                         \
        _Pragma("unroll") for (int kt = 0; kt < 2; ++kt) {                   \
          const int t0 = ((kt * 8 + 2 * c) * 64 + lane) * 8;                 \
          const int t1 = ((kt * 8 + 2 * c + 1) * 64 + lane) * 8;             \
          const f16x8 bh0 = *(const f16x8*)&w1h[t0];                         \
          const f16x8 bl0 = *(const f16x8*)&w1l[t0];                         \
          MFMA3(a10, ah[kt], al[kt], bh0, bl0)                               \
          const f16x8 bh1 = *(const f16x8*)&w1h[t1];                         \
          const f16x8 bl1 = *(const f16x8*)&w1l[t1];                         \
          MFMA3(a11, ah[kt], al[kt], bh1, bl1)                               \
        }                                                                    \
      }                                                                      \
      _Pragma("unroll") for (int j = 0; j < 4; ++j) {                        \
        cb[swz(r0 + j, cA)]      = fmaxf(a10[j], 0.f);                       \
        cb[swz(r0 + j, 16 + cA)] = fmaxf(a11[j], 0.f);                       \
      }                                                                      \
      const float4 va = *(const float4*)&cb[swz(cA, kg)];                    \
      const float4 vb = *(const float4*)&cb[swz(cA, kg + 4)];                \
      f16x8 hh, hl;                                                          \
      split44(va, vb, hh, hl);                                               \
      _Pragma("unroll") for (int n2 = 0; n2 < 4; ++n2) {                     \
        const int tt = ((c * 4 + n2) * 64 + lane) * 8;                       \
        const f16x8 bh = *(const f16x8*)&w2h[tt];                            \
        const f16x8 bl = *(const f16x8*)&w2l[tt];                            \
        MFMA3(a2[n2], hh, hl, bh, bl)                                        \
      }                                                                      \
    }                                                                        \
    _Pragma("unroll") for (int d = 0; d < 2; ++d) {                          \
      _Pragma("unroll") for (int j = 0; j < 4; ++j) {                        \
        cb[swz(r0 + j, cA)]      = fmaxf(a2[2 * d][j], 0.f);                 \
        cb[swz(r0 + j, 16 + cA)] = fmaxf(a2[2 * d + 1][j], 0.f);             \
      }                                                                      \
      const float4 va = *(const float4*)&cb[swz(cA, kg)];                    \
      const float4 vb = *(const float4*)&cb[swz(cA, kg + 4)];                \
      f16x8 hh, hl;                                                          \
      split44(va, vb, hh, hl);                                               \
      _Pragma("unroll") for (int n3 = 0; n3 < 4; ++n3) {                     \
        const int tt = ((d * 4 + n3) * 64 + lane) * 8;                       \
        const f16x8 bh = *(const f16x8*)&w3h[tt];                            \
        const f16x8 bl = *(const f16x8*)&w3l[tt];                            \
        MFMA3(acc3[n3], hh, hl, bh, bl)                                      \
      }                                                                      \
    }                                                                        \
  }

  f32x4 pacc[4];
#pragma unroll
  for (int nt = 0; nt < 4; ++nt) pacc[nt] = (f32x4){0.f, 0.f, 0.f, 0.f};

  // ---- passes 0..10 -> pacc (p=0: zero actions, L1a skipped) ----
  for (int p = 0; p < 11; ++p) {
    f16x8 ah[2], al[2];
    if (p >= 1) {
      const unsigned k0 = keys.k[2 * (p - 1)];
      const unsigned k1 = keys.k[2 * (p - 1) + 1];
      const unsigned base = (unsigned)(R0 + cA) * 64u + (unsigned)kg;
#pragma unroll
      for (int kt = 0; kt < 2; ++kt) {
        float v[8];
#pragma unroll
        for (int e = 0; e < 8; ++e) {
          unsigned o0, o1;
          tf2x32(k0, k1, 0u, base + (unsigned)(kt * 32 + e), o0, o1);
          v[e] = u01(o0 ^ o1);
        }
        split44(*(const float4*)&v[0], *(const float4*)&v[4], ah[kt], al[kt]);
      }
    }
    MLP_BODY(p != 0, pacc)
  }

  // ---- peeled with-actions pass -> pw (short live range) ----
  f32x4 pw[4];
#pragma unroll
  for (int nt = 0; nt < 4; ++nt) pw[nt] = (f32x4){0.f, 0.f, 0.f, 0.f};
  {
    f16x8 ah[2], al[2];
    const float* arow = actions + (size_t)(R0 + cA) * 64 + kg;
#pragma unroll
    for (int kt = 0; kt < 2; ++kt) {
      const float4 va = *(const float4*)(arow + kt * 32);
      const float4 vb = *(const float4*)(arow + kt * 32 + 4);
      split44(va, vb, ah[kt], al[kt]);
    }
    MLP_BODY(true, pw)
  }

  // ---- epilogue: softmax/KL per row, 16-lane shfl reductions ----
  const float inv11 = 1.0f / 11.0f;
#pragma unroll
  for (int j = 0; j < 4; ++j) {
    float pwv[4], pav[4];
#pragma unroll
    for (int nt = 0; nt < 4; ++nt) {
      pwv[nt] = pw[nt][j] + b3r[nt];
      pav[nt] = pacc[nt][j] * inv11 + b3r[nt];
    }
    float mw = fmaxf(fmaxf(pwv[0], pwv[1]), fmaxf(pwv[2], pwv[3]));
    float ma = fmaxf(fmaxf(pav[0], pav[1]), fmaxf(pav[2], pav[3]));
#pragma unroll
    for (int off = 1; off < 16; off <<= 1) {
      mw = fmaxf(mw, __shfl_xor(mw, off, 64));
      ma = fmaxf(ma, __shfl_xor(ma, off, 64));
    }
    float sw = 0.f, sa = 0.f;
#pragma unroll
    for (int nt = 0; nt < 4; ++nt) {
      sw += expf(pwv[nt] - mw);
      sa += expf(pav[nt] - ma);
    }
#pragma unroll
    for (int off = 1; off < 16; off <<= 1) {
      sw += __shfl_xor(sw, off, 64);
      sa += __shfl_xor(sa, off, 64);
    }
    const float lzw = logf(sw), lza = logf(sa);
    float contrib = 0.f;
#pragma unroll
    for (int nt = 0; nt < 4; ++nt) {
      const float lq = pav[nt] - ma - lza;
      const float lp = pwv[nt] - mw - lzw;
      contrib += expf(lq) * (lq - lp);
    }
#pragma unroll
    for (int off = 1; off < 16; off <<= 1)
      contrib += __shfl_xor(contrib, off, 64);
    if (cA == 0) out[R0 + r0 + j] = contrib * (1.0f / 64.0f);
  }
}

extern "C" void kernel_launch(void* const* d_in, const int* in_sizes, int n_in,
                              void* d_out, int out_size, void* d_ws, size_t ws_size,
                              hipStream_t stream) {
  (void)in_sizes; (void)n_in; (void)d_ws; (void)ws_size; (void)out_size;
  const float* obs     = (const float*)d_in[0];
  const float* actions = (const float*)d_in[1];
  const float* W1      = (const float*)d_in[2];
  const float* b1      = (const float*)d_in[3];
  const float* W2      = (const float*)d_in[4];
  const float* b2      = (const float*)d_in[5];
  const float* W3      = (const float*)d_in[6];
  const float* b3      = (const float*)d_in[7];

  TFKeys keys;
  for (unsigned j = 0; j < NCF; ++j) {
    unsigned o0, o1;
    tf2x32(0u, 42u, 0u, j, o0, o1);
    keys.k[2 * j]     = o0;
    keys.k[2 * j + 1] = o1;
  }

  hipLaunchKernelGGL(infl_fused, dim3(512), dim3(1024), 0, stream,
                     obs, actions, W1, b1, W2, b2, W3, b3, (float*)d_out, keys);
}